// Round 2
// baseline (202.394 us; speedup 1.0000x reference)
//
#include <hip/hip_runtime.h>

typedef __attribute__((ext_vector_type(4))) int   v4i;
typedef __attribute__((ext_vector_type(8))) short s8;     // 8 bf16
typedef __attribute__((ext_vector_type(4))) float f32x4;

#define GLB __attribute__((address_space(1)))
#define LDS __attribute__((address_space(3)))

__device__ __forceinline__ unsigned short f2bf(float f) {
  unsigned u = __builtin_bit_cast(unsigned, f);
  return (unsigned short)((u + 0x7fffu + ((u >> 16) & 1u)) >> 16);   // RNE
}

// ---- prep 1: weight [256][128][3][3] f32 -> ws_w [tap=9][co=256][ci=128] bf16
__global__ void wprep(const float* __restrict__ w, unsigned short* __restrict__ ww) {
  int o = blockIdx.x * 256 + threadIdx.x;            // 0..294911 exact
  int ci = o & 127, co = (o >> 7) & 255, tap = o >> 15;
  ww[o] = f2bf(w[(co * 128 + ci) * 9 + tap]);
}

// ---- prep 2: x f32 NCHW -> padded NHWC bf16 [32][66][66][128]; borders pre-zeroed
__global__ void xprep(const float* __restrict__ x, unsigned int* __restrict__ xw) {
  __shared__ float tile[128][65];
  int bid = blockIdx.x;                              // b*64 + h
  int b = bid >> 6, h = bid & 63;
  int t = threadIdx.x;
  {
    int wcol = t & 63, cl = t >> 6;
    const float* src = x + ((size_t)(b * 128) * 64 + h) * 64 + wcol;
#pragma unroll
    for (int j = 0; j < 32; ++j) {
      int ci = j * 4 + cl;
      tile[ci][wcol] = src[(size_t)ci * 4096];
    }
  }
  __syncthreads();
  {
    int ci2 = (t & 63) * 2, wl = t >> 6;
    unsigned int* dst = xw + (size_t)((b * 66 + h + 1) * 66) * 64;  // 64 dwords/pixel
#pragma unroll
    for (int j = 0; j < 16; ++j) {
      int wcol = j * 4 + wl;
      unsigned p = (unsigned)f2bf(tile[ci2][wcol]) |
                   ((unsigned)f2bf(tile[ci2 + 1][wcol]) << 16);
      dst[(size_t)(wcol + 1) * 64 + (t & 63)] = p;
    }
  }
}

// ---- main: implicit GEMM, tile 256co x 128pix, 8 waves (4co x 2pix),
//      double-buffered global_load_lds staging, bank-swizzled LDS
__global__ __launch_bounds__(512, 2) void conv_mfma(
    const unsigned short* __restrict__ xw, const unsigned short* __restrict__ ww,
    const float* __restrict__ bias, float* __restrict__ out) {
  // 2 buffers x 1088 slots x 16B. Pixel q=(row rr 0..3)*68+(col cc 0..67);
  // slot = q*4+g'; chunk stored at g' is g'^((q>>1)&3)  (bank swizzle)
  __shared__ unsigned short Xl[2 * 1088 * 8];
  const int tid = threadIdx.x;
  const int lane = tid & 63;
  const int wv = tid >> 6;
  const int mw = wv >> 1;                            // co base /64
  const int nw = wv & 1;                             // pix base /64
  const int l15 = lane & 15, lg = lane >> 4;
  int bid = blockIdx.x;
  bid = (bid & 7) * 128 + (bid >> 3);                // XCD-aware swizzle (1024%8==0)
  const int b = bid >> 5, h0 = (bid & 31) << 1;

  f32x4 acc[4][4];
#pragma unroll
  for (int m = 0; m < 4; ++m)
#pragma unroll
    for (int n = 0; n < 4; ++n) acc[m][n] = (f32x4){0.f, 0.f, 0.f, 0.f};

  // staging: per-thread source byte offsets (pre-swizzled), 3rd slot = wave 0 only
  unsigned soff[3];
#pragma unroll
  for (int it = 0; it < 3; ++it) {
    int s = tid + it * 512;
    if (s < 1088) {
      int q = s >> 2, g = s & 3;
      int rr = q / 68, cc = q % 68;
      if (cc > 65) cc = 65;                          // junk slots: any in-bounds addr
      int xch = g ^ ((q >> 1) & 3);
      unsigned ppix = (unsigned)((b * 66 + h0 + rr) * 66 + cc);
      soff[it] = (ppix * 128u + (unsigned)xch * 8u) * 2u;
    }
  }

  #define STAGE(buf, ci0)                                                          \
    do {                                                                           \
      const char* _sb = (const char*)xw + (unsigned)((ci0) * 2);                   \
      _Pragma("unroll")                                                            \
      for (int _it = 0; _it < 2; ++_it)                                            \
        __builtin_amdgcn_global_load_lds(                                          \
            (const GLB unsigned int*)(_sb + soff[_it]),                            \
            (LDS unsigned int*)&Xl[(buf) * 8704 + (tid + _it * 512) * 8],          \
            16, 0, 0);                                                             \
      if (wv == 0)                                                                 \
        __builtin_amdgcn_global_load_lds(                                          \
            (const GLB unsigned int*)(_sb + soff[2]),                              \
            (LDS unsigned int*)&Xl[(buf) * 8704 + (tid + 1024) * 8],               \
            16, 0, 0);                                                             \
    } while (0)

  // per-n pixel slot base (row*68+col), A element base
  int q0[4];
#pragma unroll
  for (int n = 0; n < 4; ++n) {
    int pix = nw * 64 + n * 16 + l15;
    q0[n] = (pix >> 6) * 68 + (pix & 63);
  }
  const unsigned abase = (unsigned)((mw * 64 + l15) * 128 + lg * 8);

  STAGE(0, 0);
  __syncthreads();                                   // drains vmcnt(0)

  for (int c = 0; c < 4; ++c) {                      // ci chunks of 32
    const int cur = c & 1;
    if (c < 3) STAGE(cur ^ 1, (c + 1) * 32);         // prefetch next chunk
    const unsigned ci0 = (unsigned)(c * 32);
    const char* xb = (const char*)Xl + cur * 17408;
#pragma unroll
    for (int kh = 0; kh < 3; ++kh)
#pragma unroll
      for (int kw = 0; kw < 3; ++kw) {
        const unsigned tap = (unsigned)(kh * 3 + kw);
        s8 a[4];
#pragma unroll
        for (int m = 0; m < 4; ++m)
          a[m] = *(const s8*)(ww + (tap * 32768u + (unsigned)m * 2048u + abase + ci0));
#pragma unroll
        for (int n = 0; n < 4; ++n) {
          int q = q0[n] + kh * 68 + kw;
          int off = (q * 4 + (lg ^ ((q >> 1) & 3))) * 16;
          s8 bf = *(const s8*)(xb + off);
#pragma unroll
          for (int m = 0; m < 4; ++m)
            acc[m][n] = __builtin_amdgcn_mfma_f32_16x16x32_bf16(a[m], bf, acc[m][n], 0, 0, 0);
        }
      }
    __syncthreads();                                 // next buffer ready; readers done
  }

  // ---- epilogue: + bias, store
#pragma unroll
  for (int m = 0; m < 4; ++m) {
    const int cob = mw * 64 + m * 16 + lg * 4;
    const f32x4 bi = *(const f32x4*)(bias + cob);
#pragma unroll
    for (int n = 0; n < 4; ++n) {
      int pix = nw * 64 + n * 16 + l15;
      int pr = pix >> 6, wc = pix & 63;
      size_t base = ((size_t)(b * 256 + cob) * 64 + (h0 + pr)) * 64 + wc;
#pragma unroll
      for (int r = 0; r < 4; ++r)
        out[base + (size_t)r * 4096] = acc[m][n][r] + bi[r];
    }
  }
}

// ---- fallback (ws too small): naive f32 conv, correct but slow
__global__ void conv_naive(const float* __restrict__ x, const float* __restrict__ w,
                           const float* __restrict__ bias, float* __restrict__ out) {
  int i = blockIdx.x * 256 + threadIdx.x;
  int wc = i & 63, h = (i >> 6) & 63, co = (i >> 12) & 255, b = i >> 20;
  float s = bias[co];
  for (int ci = 0; ci < 128; ++ci)
#pragma unroll
    for (int kh = 0; kh < 3; ++kh) {
      int hh = h + kh - 1;
      if ((unsigned)hh >= 64u) continue;
#pragma unroll
      for (int kw = 0; kw < 3; ++kw) {
        int wg = wc + kw - 1;
        if ((unsigned)wg >= 64u) continue;
        s += x[((b * 128 + ci) * 64 + hh) * 64 + wg] *
             w[((co * 128 + ci) * 3 + kh) * 3 + kw];
      }
    }
  out[i] = s;
}

extern "C" void kernel_launch(void* const* d_in, const int* in_sizes, int n_in,
                              void* d_out, int out_size, void* d_ws, size_t ws_size,
                              hipStream_t stream) {
  const float* x    = (const float*)d_in[0];
  const float* w    = (const float*)d_in[1];
  const float* bias = (const float*)d_in[2];
  float* out = (float*)d_out;

  const size_t X_OFF  = 1ull << 20;                            // ws_w in first 1 MB
  const size_t XBYTES = 32ull * 66 * 66 * 128 * 2;             // 35.7 MB padded NHWC
  const size_t NEED   = X_OFF + XBYTES;

  if (ws_size >= NEED) {
    unsigned short* ww = (unsigned short*)d_ws;
    unsigned short* xq = (unsigned short*)((char*)d_ws + X_OFF);
    hipMemsetAsync((void*)xq, 0, XBYTES, stream);              // zero halo borders
    hipLaunchKernelGGL(wprep, dim3(1152), dim3(256), 0, stream, w, ww);
    hipLaunchKernelGGL(xprep, dim3(2048), dim3(256), 0, stream, x, (unsigned int*)xq);
    hipLaunchKernelGGL(conv_mfma, dim3(1024), dim3(512), 0, stream, xq, ww, bias, out);
  } else {
    hipLaunchKernelGGL(conv_naive, dim3(131072), dim3(256), 0, stream, x, w, bias, out);
  }
}

// Round 3
// 150.084 us; speedup vs baseline: 1.3485x; 1.3485x over previous
//
#include <hip/hip_runtime.h>

typedef __attribute__((ext_vector_type(4))) int   v4i;
typedef __attribute__((ext_vector_type(8))) short s8;     // 8 bf16
typedef __attribute__((ext_vector_type(4))) float f32x4;
typedef __attribute__((ext_vector_type(16))) float f32x16;

#define GLB __attribute__((address_space(1)))
#define LDS __attribute__((address_space(3)))

__device__ __forceinline__ unsigned short f2bf(float f) {
  unsigned u = __builtin_bit_cast(unsigned, f);
  return (unsigned short)((u + 0x7fffu + ((u >> 16) & 1u)) >> 16);   // RNE
}

// ---- prep 1: weight [256][128][3][3] f32 -> ws_w [tap=9][co=256][ci=128] bf16
__global__ void wprep(const float* __restrict__ w, unsigned short* __restrict__ ww) {
  int o = blockIdx.x * 256 + threadIdx.x;            // 0..294911 exact
  int ci = o & 127, co = (o >> 7) & 255, tap = o >> 15;
  ww[o] = f2bf(w[(co * 128 + ci) * 9 + tap]);
}

// ---- prep 2: x f32 NCHW -> padded NHWC bf16 [32][66][66][128]; writes own borders
__global__ void xprep(const float* __restrict__ x, unsigned int* __restrict__ xw) {
  __shared__ float tile[128][65];
  int bid = blockIdx.x;                              // b*64 + h
  int b = bid >> 6, h = bid & 63;
  int t = threadIdx.x;
  {
    int wcol = t & 63, cl = t >> 6;
    const float* src = x + ((size_t)(b * 128) * 64 + h) * 64 + wcol;
#pragma unroll
    for (int j = 0; j < 32; ++j) {
      int ci = j * 4 + cl;
      tile[ci][wcol] = src[(size_t)ci * 4096];
    }
  }
  unsigned int* dst = xw + (size_t)((b * 66 + h + 1) * 66) * 64;   // 64 dwords/pixel
  // halo borders owned by this block (no big memset):
  if (t < 128) {                                     // cols 0 and 65 of this row
    int col = (t >> 6) ? 65 : 0;
    dst[(size_t)col * 64 + (t & 63)] = 0u;
  }
  if (h == 0 || h == 63) {                           // rows 0 / 65 of this batch
    unsigned int* rb = xw + (size_t)(b * 66 + (h == 0 ? 0 : 65)) * 66 * 64;
    for (int j = t; j < 66 * 64; j += 256) rb[j] = 0u;
  }
  __syncthreads();
  {
    int ci2 = (t & 63) * 2, wl = t >> 6;
#pragma unroll
    for (int j = 0; j < 16; ++j) {
      int wcol = j * 4 + wl;
      unsigned p = (unsigned)f2bf(tile[ci2][wcol]) |
                   ((unsigned)f2bf(tile[ci2 + 1][wcol]) << 16);
      dst[(size_t)(wcol + 1) * 64 + (t & 63)] = p;
    }
  }
}

// ---- main: implicit GEMM, tile 256co x 256pix (4 rows), 8 waves (4mw x 2nw),
//      wave = 64co x 128pix via 32x32x16 MFMA, dbuf global_load_lds staging
__global__ __launch_bounds__(512, 2) void conv_mfma(
    const unsigned short* __restrict__ xw, const unsigned short* __restrict__ ww,
    const float* __restrict__ bias, float* __restrict__ out) {
  // per buffer: 408 pixel-slots (6 rows x 68 cols) x 4 chunks x 16B = 26112 B
  // chunk g of pixel q stored at slot position g ^ ((q>>1)&3)  (bank swizzle)
  __shared__ unsigned short Xl[2 * 13056];
  const int tid = threadIdx.x;
  const int lane = tid & 63;
  const int l31 = lane & 31, lh = lane >> 5;         // row/col, k-half
  const int wv = tid >> 6;
  const int mw = wv & 3;                             // co group *64
  const int nw = wv >> 2;                            // pixel group *128
  int bid = blockIdx.x;
  bid = (bid & 7) * 64 + (bid >> 3);                 // XCD swizzle (512%8==0)
  const int b = bid >> 4, h0 = (bid & 15) << 2;

  f32x16 acc[2][4];
#pragma unroll
  for (int m = 0; m < 2; ++m)
#pragma unroll
    for (int n = 0; n < 4; ++n)
#pragma unroll
      for (int e = 0; e < 16; ++e) acc[m][n][e] = 0.f;

  // ---- staging source offsets (pre-swizzled), 1632 slots = 3*512 + 96
  unsigned soff[4];
#pragma unroll
  for (int it = 0; it < 4; ++it) {
    int s = tid + it * 512;
    soff[it] = 0;
    if (s < 1632) {
      int q = s >> 2, gpos = s & 3;
      int rr = q / 68, cc = q - rr * 68;
      if (cc > 65) cc = 65;                          // junk slots: in-bounds addr
      int g = gpos ^ ((q >> 1) & 3);
      soff[it] = ((unsigned)((b * 66 + h0 + rr) * 66 + cc) * 128u + (unsigned)g * 8u) * 2u;
    }
  }

  #define STAGE(buf, ci0)                                                      \
    do {                                                                       \
      const char* _sb = (const char*)xw + (unsigned)((ci0) * 2);               \
      _Pragma("unroll")                                                        \
      for (int _it = 0; _it < 3; ++_it)                                        \
        __builtin_amdgcn_global_load_lds(                                      \
            (const GLB unsigned int*)(_sb + soff[_it]),                        \
            (LDS unsigned int*)&Xl[(buf) * 13056 + (tid + _it * 512) * 8],     \
            16, 0, 0);                                                         \
      if (tid < 96)                                                            \
        __builtin_amdgcn_global_load_lds(                                      \
            (const GLB unsigned int*)(_sb + soff[3]),                          \
            (LDS unsigned int*)&Xl[(buf) * 13056 + (tid + 1536) * 8],          \
            16, 0, 0);                                                         \
    } while (0)

  // per-n pixel slot bases: pix = nw*128 + n*32 + l31 -> q = row*68 + col + 1-off taps
  int qb[4];
#pragma unroll
  for (int n = 0; n < 4; ++n) {
    int pixb = nw * 128 + n * 32;
    qb[n] = (pixb >> 6) * 68 + (pixb & 63) + l31;
  }
  const unsigned abase = (unsigned)(mw * 64 + l31) * 128u + (unsigned)lh * 8u;

  STAGE(0, 0);
  __syncthreads();

  for (int c = 0; c < 4; ++c) {                      // ci chunks of 32
    const int cur = c & 1;
    if (c < 3) STAGE(cur ^ 1, (c + 1) * 32);
    const unsigned ci0 = (unsigned)(c * 32);
    const char* xb = (const char*)Xl + cur * 26112;
    const unsigned wb0 = abase + ci0;

    // tap-0 A prefetch (a[kk][m]): ci = ci0 + kk*16 + lh*8, co = mw*64+m*32+l31
    s8 a00 = *(const s8*)(ww + wb0);
    s8 a01 = *(const s8*)(ww + wb0 + 4096u);
    s8 a10 = *(const s8*)(ww + wb0 + 16u);
    s8 a11 = *(const s8*)(ww + wb0 + 4112u);
#pragma unroll
    for (int tap = 0; tap < 9; ++tap) {
      s8 c00 = a00, c01 = a01, c10 = a10, c11 = a11;
      if (tap < 8) {                                 // next-tap A prefetch
        const unsigned nb = wb0 + (unsigned)(tap + 1) * 32768u;
        a00 = *(const s8*)(ww + nb);
        a01 = *(const s8*)(ww + nb + 4096u);
        a10 = *(const s8*)(ww + nb + 16u);
        a11 = *(const s8*)(ww + nb + 4112u);
      }
      const int kh = tap / 3, kw = tap - kh * 3;
#pragma unroll
      for (int n = 0; n < 4; ++n) {
        int q = qb[n] + kh * 68 + kw;
        int xq = (q >> 1) & 3;
        const char* pb = xb + q * 64;
        s8 b0 = *(const s8*)(pb + ((0 + lh) ^ xq) * 16);   // kk=0
        s8 b1 = *(const s8*)(pb + ((2 + lh) ^ xq) * 16);   // kk=1
        acc[0][n] = __builtin_amdgcn_mfma_f32_32x32x16_bf16(c00, b0, acc[0][n], 0, 0, 0);
        acc[1][n] = __builtin_amdgcn_mfma_f32_32x32x16_bf16(c01, b0, acc[1][n], 0, 0, 0);
        acc[0][n] = __builtin_amdgcn_mfma_f32_32x32x16_bf16(c10, b1, acc[0][n], 0, 0, 0);
        acc[1][n] = __builtin_amdgcn_mfma_f32_32x32x16_bf16(c11, b1, acc[1][n], 0, 0, 0);
      }
    }
    __syncthreads();
  }

  // ---- epilogue: D row = (reg&3) + 8*(reg>>2) + 4*lh, col = l31 (pixel)
#pragma unroll
  for (int m = 0; m < 2; ++m)
#pragma unroll
    for (int rq = 0; rq < 4; ++rq) {
      const int cob = mw * 64 + m * 32 + 8 * rq + 4 * lh;
      const f32x4 bi = *(const f32x4*)(bias + cob);
#pragma unroll
      for (int n = 0; n < 4; ++n) {
        int pix = nw * 128 + n * 32 + l31;
        int pr = pix >> 6, wc = pix & 63;
        size_t base = ((size_t)(b * 256 + cob) * 64 + (h0 + pr)) * 64 + wc;
#pragma unroll
        for (int e = 0; e < 4; ++e)
          out[base + (size_t)e * 4096] = acc[m][n][rq * 4 + e] + bi[e];
      }
    }
}

// ---- fallback (ws too small): naive f32 conv, correct but slow
__global__ void conv_naive(const float* __restrict__ x, const float* __restrict__ w,
                           const float* __restrict__ bias, float* __restrict__ out) {
  int i = blockIdx.x * 256 + threadIdx.x;
  int wc = i & 63, h = (i >> 6) & 63, co = (i >> 12) & 255, b = i >> 20;
  float s = bias[co];
  for (int ci = 0; ci < 128; ++ci)
#pragma unroll
    for (int kh = 0; kh < 3; ++kh) {
      int hh = h + kh - 1;
      if ((unsigned)hh >= 64u) continue;
#pragma unroll
      for (int kw = 0; kw < 3; ++kw) {
        int wg = wc + kw - 1;
        if ((unsigned)wg >= 64u) continue;
        s += x[((b * 128 + ci) * 64 + hh) * 64 + wg] *
             w[((co * 128 + ci) * 3 + kh) * 3 + kw];
      }
    }
  out[i] = s;
}

extern "C" void kernel_launch(void* const* d_in, const int* in_sizes, int n_in,
                              void* d_out, int out_size, void* d_ws, size_t ws_size,
                              hipStream_t stream) {
  const float* x    = (const float*)d_in[0];
  const float* w    = (const float*)d_in[1];
  const float* bias = (const float*)d_in[2];
  float* out = (float*)d_out;

  const size_t X_OFF  = 1ull << 20;                            // ws_w in first 1 MB
  const size_t XBYTES = 32ull * 66 * 66 * 128 * 2;             // 35.7 MB padded NHWC
  const size_t NEED   = X_OFF + XBYTES;

  if (ws_size >= NEED) {
    unsigned short* ww = (unsigned short*)d_ws;
    unsigned short* xq = (unsigned short*)((char*)d_ws + X_OFF);
    hipLaunchKernelGGL(wprep, dim3(1152), dim3(256), 0, stream, w, ww);
    hipLaunchKernelGGL(xprep, dim3(2048), dim3(256), 0, stream, x, (unsigned int*)xq);
    hipLaunchKernelGGL(conv_mfma, dim3(512), dim3(512), 0, stream, xq, ww, bias, out);
  } else {
    hipLaunchKernelGGL(conv_naive, dim3(131072), dim3(256), 0, stream, x, w, bias, out);
  }
}